// Round 1
// baseline (7616.419 us; speedup 1.0000x reference)
//
#include <hip/hip_runtime.h>
#include <float.h>
#include <math.h>

namespace {

constexpr int NB = 16;      // batch
constexpr int NP = 2048;    // points per cloud
constexpr int KK = 20;      // neighbors
constexpr int SBLK = 1024;  // edge stats grid
constexpr int ABLK = 2048;  // edge apply grid
constexpr int FBLK = 512;   // final stats grid

__device__ __forceinline__ void atomicMaxFloat(float* addr, float val) {
    if (val >= 0.f) atomicMax((int*)addr, __float_as_int(val));
    else            atomicMin((unsigned int*)addr, __float_as_uint(val));
}

// ---------------- squared norms ----------------
__global__ __launch_bounds__(256) void sq_kernel(const float* __restrict__ x, int ldx, int d,
                                                 float* __restrict__ sq) {
    int i = blockIdx.x * 256 + threadIdx.x;
    if (i < NB * NP) {
        const float* row = x + (size_t)i * ldx;
        float s = 0.f;
        for (int j = 0; j < d; ++j) s += row[j] * row[j];
        sq[i] = s;
    }
}

// ---------------- kNN: one block (256 thr) per point ----------------
template <int D>
__global__ __launch_bounds__(256) void knn_kernel(const float* __restrict__ x, int ldx,
                                                  const float* __restrict__ sq,
                                                  int* __restrict__ idx_out) {
    __shared__ float dist[NP];
    __shared__ float xs[D];
    __shared__ float lv[256];
    __shared__ int   li[256];
    __shared__ int   winner;
    const int p = blockIdx.x;
    const int b = p / NP;
    const int n = p - b * NP;
    const int tid = threadIdx.x;
    const float* xb = x + (size_t)b * NP * ldx;
    if (tid < D) xs[tid] = xb[(size_t)n * ldx + tid];
    __syncthreads();
    const float sqn = sq[p];
    const float* sqb = sq + (size_t)b * NP;
    for (int m = tid; m < NP; m += 256) {
        const float* xm = xb + (size_t)m * ldx;
        float dot = 0.f;
        if constexpr (D % 4 == 0) {
            #pragma unroll
            for (int j = 0; j < D; j += 4) {
                float4 v = *reinterpret_cast<const float4*>(xm + j);
                dot += xs[j] * v.x + xs[j + 1] * v.y + xs[j + 2] * v.z + xs[j + 3] * v.w;
            }
        } else {
            #pragma unroll
            for (int j = 0; j < D; ++j) dot += xs[j] * xm[j];
        }
        dist[m] = sqn + sqb[m] - 2.f * dot;
    }
    __syncthreads();
    // initial per-thread local min over strided slots
    float bv = FLT_MAX; int bi = NP;
    for (int m = tid; m < NP; m += 256) {
        float v = dist[m];
        if (v < bv) { bv = v; bi = m; }
    }
    lv[tid] = bv; li[tid] = bi;
    __syncthreads();
    for (int t = 0; t < KK; ++t) {
        if (tid < 64) {
            float v = lv[tid]; int i = li[tid];
            #pragma unroll
            for (int u = 1; u < 4; ++u) {
                float v2 = lv[tid + u * 64]; int i2 = li[tid + u * 64];
                if (v2 < v || (v2 == v && i2 < i)) { v = v2; i = i2; }
            }
            #pragma unroll
            for (int s = 32; s > 0; s >>= 1) {
                float v2 = __shfl_down(v, s); int i2 = __shfl_down(i, s);
                if (v2 < v || (v2 == v && i2 < i)) { v = v2; i = i2; }
            }
            if (tid == 0) { idx_out[(size_t)p * KK + t] = i; winner = i; dist[i] = FLT_MAX; }
        }
        __syncthreads();
        const int w = winner;
        if ((w & 255) == tid) {  // only the owner's local min changed
            float nv = FLT_MAX; int ni = NP;
            for (int m = tid; m < NP; m += 256) {
                float v = dist[m];
                if (v < nv) { nv = v; ni = m; }
            }
            lv[tid] = nv; li[tid] = ni;
        }
        __syncthreads();
    }
}

// ---------------- Wd[j][c] = W[j][c] - W[d+j][c] ----------------
__global__ __launch_bounds__(256) void wd_kernel(const float* __restrict__ W, float* __restrict__ Wd,
                                                 int d, int C) {
    int i = blockIdx.x * 256 + threadIdx.x;
    if (i < d * C) {
        int j = i / C, c = i - j * C;
        Wd[i] = W[j * C + c] - W[(d + j) * C + c];
    }
}

// ---------------- edge conv pass 1: per-channel sums of h ----------------
template <int D, int C>
__global__ __launch_bounds__(256) void edge_stats_kernel(
        const float* __restrict__ x, int ldx,
        const int* __restrict__ idx,
        const float* __restrict__ W, const float* __restrict__ Wd,
        float* __restrict__ psum, float* __restrict__ psum2) {
    constexpr int KSTEP = 256 / C;
    __shared__ float xi[D];
    __shared__ float xjs[KK][D];
    __shared__ float base[C];
    __shared__ float red[256];
    __shared__ int nidx[KK];
    const int tid = threadIdx.x;
    const int c = tid % C;
    const int kg = tid / C;
    float s1 = 0.f, s2 = 0.f;
    for (int p = blockIdx.x; p < NB * NP; p += SBLK) {
        const int b = p / NP;
        const float* xb = x + (size_t)b * NP * ldx;
        __syncthreads();
        if (tid < D) xi[tid] = x[(size_t)p * ldx + tid];
        if (tid >= 128 && tid < 128 + KK) nidx[tid - 128] = idx[(size_t)p * KK + (tid - 128)];
        __syncthreads();
        for (int i = tid; i < KK * D; i += 256) {
            int k = i / D, j = i - k * D;
            xjs[k][j] = xb[(size_t)nidx[k] * ldx + j];
        }
        if (tid < C) {
            float s = 0.f;
            #pragma unroll
            for (int j = 0; j < D; ++j) s += xi[j] * Wd[j * C + tid];
            base[tid] = s;
        }
        __syncthreads();
        for (int k = kg; k < KK; k += KSTEP) {
            float h = base[c];
            #pragma unroll
            for (int j = 0; j < D; ++j) h += xjs[k][j] * W[(D + j) * C + c];
            s1 += h; s2 += h * h;
        }
    }
    red[tid] = s1;
    __syncthreads();
    if (tid < C) {
        float t = red[tid];
        #pragma unroll
        for (int u = 1; u < KSTEP; ++u) t += red[tid + u * C];
        psum[(size_t)blockIdx.x * C + tid] = t;
    }
    __syncthreads();
    red[tid] = s2;
    __syncthreads();
    if (tid < C) {
        float t = red[tid];
        #pragma unroll
        for (int u = 1; u < KSTEP; ++u) t += red[tid + u * C];
        psum2[(size_t)blockIdx.x * C + tid] = t;
    }
}

// ---------------- BN stats reduce -> alpha/beta ----------------
__global__ __launch_bounds__(256) void bn_reduce_kernel(
        const float* __restrict__ psum, const float* __restrict__ psum2,
        int npart, int C, const float* __restrict__ g, const float* __restrict__ bb,
        float inv_cnt, float* __restrict__ alpha, float* __restrict__ beta) {
    const int c = blockIdx.x;
    const int tid = threadIdx.x;
    __shared__ float r1[256], r2[256];
    float s1 = 0.f, s2 = 0.f;
    for (int i = tid; i < npart; i += 256) {
        s1 += psum[(size_t)i * C + c];
        s2 += psum2[(size_t)i * C + c];
    }
    r1[tid] = s1; r2[tid] = s2;
    __syncthreads();
    for (int s = 128; s > 0; s >>= 1) {
        if (tid < s) { r1[tid] += r1[tid + s]; r2[tid] += r2[tid + s]; }
        __syncthreads();
    }
    if (tid == 0) {
        float mean = r1[0] * inv_cnt;
        float var = r2[0] * inv_cnt - mean * mean;
        float a = g[c] * rsqrtf(var + 1e-5f);
        alpha[c] = a;
        beta[c] = bb[c] - mean * a;
    }
}

// ---------------- edge conv pass 2: recompute, BN affine, leaky, max over k ----------------
template <int D, int C>
__global__ __launch_bounds__(256) void edge_apply_kernel(
        const float* __restrict__ x, int ldx,
        const int* __restrict__ idx,
        const float* __restrict__ W, const float* __restrict__ Wd,
        const float* __restrict__ alpha, const float* __restrict__ beta,
        float* __restrict__ out, int ldo) {
    constexpr int KSTEP = 256 / C;
    __shared__ float xi[D];
    __shared__ float xjs[KK][D];
    __shared__ float base[C];
    __shared__ float red[256];
    __shared__ int nidx[KK];
    const int tid = threadIdx.x;
    const int c = tid % C;
    const int kg = tid / C;
    for (int p = blockIdx.x; p < NB * NP; p += ABLK) {
        const int b = p / NP;
        const float* xb = x + (size_t)b * NP * ldx;
        __syncthreads();
        if (tid < D) xi[tid] = x[(size_t)p * ldx + tid];
        if (tid >= 128 && tid < 128 + KK) nidx[tid - 128] = idx[(size_t)p * KK + (tid - 128)];
        __syncthreads();
        for (int i = tid; i < KK * D; i += 256) {
            int k = i / D, j = i - k * D;
            xjs[k][j] = xb[(size_t)nidx[k] * ldx + j];
        }
        if (tid < C) {
            float s = 0.f;
            #pragma unroll
            for (int j = 0; j < D; ++j) s += xi[j] * Wd[j * C + tid];
            base[tid] = s;
        }
        __syncthreads();
        float lmax = -FLT_MAX;
        const float a = alpha[c], be = beta[c];
        for (int k = kg; k < KK; k += KSTEP) {
            float h = base[c];
            #pragma unroll
            for (int j = 0; j < D; ++j) h += xjs[k][j] * W[(D + j) * C + c];
            float y = a * h + be;
            y = fmaxf(y, 0.2f * y);
            lmax = fmaxf(lmax, y);
        }
        red[tid] = lmax;
        __syncthreads();
        if (tid < C) {
            float m = red[tid];
            #pragma unroll
            for (int u = 1; u < KSTEP; ++u) m = fmaxf(m, red[tid + u * C]);
            out[(size_t)p * ldo + tid] = m;
        }
    }
}

// ---------------- conv_final pass 1: stats of xc@Wf ----------------
__global__ __launch_bounds__(256) void final_stats_kernel(
        const float* __restrict__ xc, const float* __restrict__ Wf,
        float* __restrict__ psum, float* __restrict__ psum2) {
    __shared__ float rows[8][256];
    const int tid = threadIdx.x;
    float s1[4] = {0.f, 0.f, 0.f, 0.f};
    float s2[4] = {0.f, 0.f, 0.f, 0.f};
    for (int t0 = blockIdx.x * 8; t0 < NB * NP; t0 += FBLK * 8) {
        __syncthreads();
        for (int i = tid; i < 8 * 256; i += 256) rows[i >> 8][i & 255] = xc[(size_t)t0 * 256 + i];
        __syncthreads();
        float h[4][8];
        #pragma unroll
        for (int i = 0; i < 4; ++i)
            #pragma unroll
            for (int q = 0; q < 8; ++q) h[i][q] = 0.f;
        for (int e = 0; e < 256; ++e) {
            float r[8];
            #pragma unroll
            for (int q = 0; q < 8; ++q) r[q] = rows[q][e];
            #pragma unroll
            for (int i = 0; i < 4; ++i) {
                float w = Wf[(size_t)e * 1024 + tid + i * 256];
                #pragma unroll
                for (int q = 0; q < 8; ++q) h[i][q] += r[q] * w;
            }
        }
        #pragma unroll
        for (int i = 0; i < 4; ++i)
            #pragma unroll
            for (int q = 0; q < 8; ++q) { s1[i] += h[i][q]; s2[i] += h[i][q] * h[i][q]; }
    }
    #pragma unroll
    for (int i = 0; i < 4; ++i) {
        psum[(size_t)blockIdx.x * 1024 + tid + i * 256] = s1[i];
        psum2[(size_t)blockIdx.x * 1024 + tid + i * 256] = s2[i];
    }
}

// ---------------- conv_final pass 2 + global max pool ----------------
__global__ __launch_bounds__(256) void final_apply_kernel(
        const float* __restrict__ xc, const float* __restrict__ Wf,
        const float* __restrict__ alpha, const float* __restrict__ beta,
        float* __restrict__ gfeat) {
    __shared__ float rows[8][256];
    const int tid = threadIdx.x;
    const int p0 = blockIdx.x * 8;
    const int b = p0 / NP;
    for (int i = tid; i < 8 * 256; i += 256) rows[i >> 8][i & 255] = xc[(size_t)p0 * 256 + i];
    __syncthreads();
    float h[4][8];
    #pragma unroll
    for (int i = 0; i < 4; ++i)
        #pragma unroll
        for (int q = 0; q < 8; ++q) h[i][q] = 0.f;
    for (int e = 0; e < 256; ++e) {
        float r[8];
        #pragma unroll
        for (int q = 0; q < 8; ++q) r[q] = rows[q][e];
        #pragma unroll
        for (int i = 0; i < 4; ++i) {
            float w = Wf[(size_t)e * 1024 + tid + i * 256];
            #pragma unroll
            for (int q = 0; q < 8; ++q) h[i][q] += r[q] * w;
        }
    }
    #pragma unroll
    for (int i = 0; i < 4; ++i) {
        const int c = tid + i * 256;
        const float a = alpha[c], be = beta[c];
        float m = -FLT_MAX;
        #pragma unroll
        for (int q = 0; q < 8; ++q) {
            float y = a * h[i][q] + be;
            y = fmaxf(y, 0.2f * y);
            m = fmaxf(m, y);
        }
        atomicMaxFloat(&gfeat[(size_t)b * 1024 + c], m);
    }
}

__global__ __launch_bounds__(256) void fill_kernel(float* __restrict__ p, float v, int n) {
    int i = blockIdx.x * 256 + threadIdx.x;
    if (i < n) p[i] = v;
}

// ---------------- tiny classifier ----------------
__global__ __launch_bounds__(256) void gemm_small(const float* __restrict__ A,
                                                  const float* __restrict__ W,
                                                  const float* __restrict__ bias,
                                                  float* __restrict__ out,
                                                  int M, int Kd, int Nd) {
    int i = blockIdx.x * 256 + threadIdx.x;
    if (i < M * Nd) {
        int m = i / Nd, c = i - m * Nd;
        float s = bias[c];
        const float* a = A + (size_t)m * Kd;
        for (int e = 0; e < Kd; ++e) s += a[e] * W[(size_t)e * Nd + c];
        out[i] = s;
    }
}

__global__ __launch_bounds__(256) void bn_rows_kernel(const float* __restrict__ z,
                                                      const float* __restrict__ g,
                                                      const float* __restrict__ bb,
                                                      float* __restrict__ out, int C) {
    int c = blockIdx.x * 256 + threadIdx.x;
    if (c < C) {
        float s = 0.f, s2 = 0.f;
        for (int b = 0; b < NB; ++b) {
            float v = z[(size_t)b * C + c];
            s += v; s2 += v * v;
        }
        float mean = s * (1.f / NB);
        float var = s2 * (1.f / NB) - mean * mean;
        float a = g[c] * rsqrtf(var + 1e-5f);
        float be = bb[c] - mean * a;
        for (int b = 0; b < NB; ++b) {
            float v = a * z[(size_t)b * C + c] + be;
            out[(size_t)b * C + c] = fmaxf(v, 0.2f * v);
        }
    }
}

struct Ws {
    int* idx; float* sq; float* xc; float* wd;
    float* psum; float* psum2; float* alpha; float* beta;
    float* gfeat; float* z4; float* h4; float* z5; float* h5;
};

template <int D, int C>
static void run_edge_layer(const float* x, int ldx,
                           const float* W, const float* g, const float* bb,
                           float* out, const Ws& w, hipStream_t stream) {
    const int total = NB * NP;
    sq_kernel<<<(total + 255) / 256, 256, 0, stream>>>(x, ldx, D, w.sq);
    knn_kernel<D><<<total, 256, 0, stream>>>(x, ldx, w.sq, w.idx);
    wd_kernel<<<(D * C + 255) / 256, 256, 0, stream>>>(W, w.wd, D, C);
    edge_stats_kernel<D, C><<<SBLK, 256, 0, stream>>>(x, ldx, w.idx, W, w.wd, w.psum, w.psum2);
    bn_reduce_kernel<<<C, 256, 0, stream>>>(w.psum, w.psum2, SBLK, C, g, bb,
                                            1.f / (float)(NB * NP * KK), w.alpha, w.beta);
    edge_apply_kernel<D, C><<<ABLK, 256, 0, stream>>>(x, ldx, w.idx, W, w.wd,
                                                      w.alpha, w.beta, out, 256);
}

} // namespace

extern "C" void kernel_launch(void* const* d_in, const int* in_sizes, int n_in,
                              void* d_out, int out_size, void* d_ws, size_t ws_size,
                              hipStream_t stream) {
    (void)in_sizes; (void)n_in; (void)out_size; (void)ws_size;
    const float* pos = (const float*)d_in[0];
    const float* W1  = (const float*)d_in[1];
    const float* g1  = (const float*)d_in[2];
    const float* b1  = (const float*)d_in[3];
    const float* W2  = (const float*)d_in[4];
    const float* g2  = (const float*)d_in[5];
    const float* b2  = (const float*)d_in[6];
    const float* W3  = (const float*)d_in[7];
    const float* g3  = (const float*)d_in[8];
    const float* b3  = (const float*)d_in[9];
    const float* Wf  = (const float*)d_in[10];
    const float* gf  = (const float*)d_in[11];
    const float* bf  = (const float*)d_in[12];
    const float* W4  = (const float*)d_in[13];
    const float* b4  = (const float*)d_in[14];
    const float* g4  = (const float*)d_in[15];
    const float* be4 = (const float*)d_in[16];
    const float* W5  = (const float*)d_in[17];
    const float* b5  = (const float*)d_in[18];
    const float* g5  = (const float*)d_in[19];
    const float* be5 = (const float*)d_in[20];
    const float* W6  = (const float*)d_in[21];
    const float* b6  = (const float*)d_in[22];
    float* out = (float*)d_out;

    float* ws = (float*)d_ws;
    size_t off = 0;
    Ws w;
    w.idx   = (int*)ws;            off += (size_t)NB * NP * KK;   // 655360
    w.sq    = ws + off;            off += (size_t)NB * NP;        // 32768
    w.xc    = ws + off;            off += (size_t)NB * NP * 256;  // 8388608
    w.wd    = ws + off;            off += 64 * 128;               // 8192
    w.psum  = ws + off;            off += (size_t)1024 * 1024;
    w.psum2 = ws + off;            off += (size_t)1024 * 1024;
    w.alpha = ws + off;            off += 1024;
    w.beta  = ws + off;            off += 1024;
    w.gfeat = ws + off;            off += NB * 1024;
    w.z4    = ws + off;            off += NB * 512;
    w.h4    = ws + off;            off += NB * 512;
    w.z5    = ws + off;            off += NB * 256;
    w.h5    = ws + off;            off += NB * 256;

    // EdgeConv 1: pos[B,N,3] -> xc[:, :, 0:64]
    run_edge_layer<3, 64>(pos, 3, W1, g1, b1, w.xc + 0, w, stream);
    // EdgeConv 2: x1 -> xc[:, :, 64:128]
    run_edge_layer<64, 64>(w.xc + 0, 256, W2, g2, b2, w.xc + 64, w, stream);
    // EdgeConv 3: x2 -> xc[:, :, 128:256]
    run_edge_layer<64, 128>(w.xc + 64, 256, W3, g3, b3, w.xc + 128, w, stream);

    // conv_final: xc[B,N,256] @ Wf[256,1024] -> BN -> leaky -> max over N
    final_stats_kernel<<<FBLK, 256, 0, stream>>>(w.xc, Wf, w.psum, w.psum2);
    bn_reduce_kernel<<<1024, 256, 0, stream>>>(w.psum, w.psum2, FBLK, 1024, gf, bf,
                                               1.f / (float)(NB * NP), w.alpha, w.beta);
    fill_kernel<<<(NB * 1024 + 255) / 256, 256, 0, stream>>>(w.gfeat, -INFINITY, NB * 1024);
    final_apply_kernel<<<NB * NP / 8, 256, 0, stream>>>(w.xc, Wf, w.alpha, w.beta, w.gfeat);

    // classifier
    gemm_small<<<(NB * 512 + 255) / 256, 256, 0, stream>>>(w.gfeat, W4, b4, w.z4, NB, 1024, 512);
    bn_rows_kernel<<<2, 256, 0, stream>>>(w.z4, g4, be4, w.h4, 512);
    gemm_small<<<(NB * 256 + 255) / 256, 256, 0, stream>>>(w.h4, W5, b5, w.z5, NB, 512, 256);
    bn_rows_kernel<<<1, 256, 0, stream>>>(w.z5, g5, be5, w.h5, 256);
    gemm_small<<<(NB * 40 + 255) / 256, 256, 0, stream>>>(w.h5, W6, b6, out, NB, 256, 40);
}

// Round 2
// 3575.516 us; speedup vs baseline: 2.1302x; 2.1302x over previous
//
#include <hip/hip_runtime.h>
#include <float.h>
#include <math.h>

namespace {

constexpr int NB = 16;
constexpr int NP = 2048;
constexpr int KK = 20;
constexpr int TOT = NB * NP;   // 32768
constexpr int EBLK = 1024;     // edge pass grid

__device__ __forceinline__ float leaky(float v) { return fmaxf(v, 0.2f * v); }

// ---------------- pos -> pos4 (pad to 4 comps) ----------------
__global__ __launch_bounds__(256) void pos4_kernel(const float* __restrict__ pos,
                                                   float* __restrict__ pos4) {
    int i = blockIdx.x * 256 + threadIdx.x;
    if (i < TOT) {
        pos4[i * 4 + 0] = pos[i * 3 + 0];
        pos4[i * 4 + 1] = pos[i * 3 + 1];
        pos4[i * 4 + 2] = pos[i * 3 + 2];
        pos4[i * 4 + 3] = 0.f;
    }
}

// ---------------- squared norms (float4 rows) ----------------
__global__ __launch_bounds__(256) void sq4_kernel(const float* __restrict__ x, int ldx, int nj4,
                                                  float* __restrict__ sq) {
    int i = blockIdx.x * 256 + threadIdx.x;
    if (i < TOT) {
        const float4* r = reinterpret_cast<const float4*>(x + (size_t)i * ldx);
        float s = 0.f;
        for (int j4 = 0; j4 < nj4; ++j4) {
            float4 v = r[j4];
            s += v.x * v.x + v.y * v.y + v.z * v.z + v.w * v.w;
        }
        sq[i] = s;
    }
}

// ---------------- kNN: 4 queries per block ----------------
template <int NJ4>
__global__ __launch_bounds__(256) void knn4_kernel(const float* __restrict__ x, int ldx,
                                                   const float* __restrict__ sq,
                                                   int* __restrict__ idx_out) {
    __shared__ float dist[4][NP];    // 32 KB
    __shared__ float4 qv[4][NJ4];
    __shared__ float sqq[4];
    const int tid = threadIdx.x;
    const int q0 = blockIdx.x * 4;           // global query index base
    const int b = q0 / NP;
    const int bofs = b * NP;
    const float* xb = x + (size_t)bofs * ldx;
    if (tid < 4 * NJ4) {
        int q = tid / NJ4, j4 = tid % NJ4;
        int n = q0 + q - bofs;
        qv[q][j4] = *reinterpret_cast<const float4*>(xb + (size_t)n * ldx + j4 * 4);
    }
    if (tid < 4) sqq[tid] = sq[q0 + tid];
    __syncthreads();
    const float* sqb = sq + bofs;
    // two candidates per iteration for better FMA:LDS ratio
    for (int m = tid; m < NP; m += 512) {
        const int m2 = m + 256;
        const float* xm0 = xb + (size_t)m * ldx;
        const float* xm1 = xb + (size_t)m2 * ldx;
        float d00 = 0.f, d01 = 0.f, d02 = 0.f, d03 = 0.f;
        float d10 = 0.f, d11 = 0.f, d12 = 0.f, d13 = 0.f;
        #pragma unroll
        for (int j4 = 0; j4 < NJ4; ++j4) {
            float4 c0 = *reinterpret_cast<const float4*>(xm0 + j4 * 4);
            float4 c1 = *reinterpret_cast<const float4*>(xm1 + j4 * 4);
            float4 a0 = qv[0][j4];
            d00 += a0.x * c0.x + a0.y * c0.y + a0.z * c0.z + a0.w * c0.w;
            d10 += a0.x * c1.x + a0.y * c1.y + a0.z * c1.z + a0.w * c1.w;
            float4 a1 = qv[1][j4];
            d01 += a1.x * c0.x + a1.y * c0.y + a1.z * c0.z + a1.w * c0.w;
            d11 += a1.x * c1.x + a1.y * c1.y + a1.z * c1.z + a1.w * c1.w;
            float4 a2 = qv[2][j4];
            d02 += a2.x * c0.x + a2.y * c0.y + a2.z * c0.z + a2.w * c0.w;
            d12 += a2.x * c1.x + a2.y * c1.y + a2.z * c1.z + a2.w * c1.w;
            float4 a3 = qv[3][j4];
            d03 += a3.x * c0.x + a3.y * c0.y + a3.z * c0.z + a3.w * c0.w;
            d13 += a3.x * c1.x + a3.y * c1.y + a3.z * c1.z + a3.w * c1.w;
        }
        float s0 = sqb[m], s1v = sqb[m2];
        dist[0][m] = sqq[0] + s0 - 2.f * d00;
        dist[1][m] = sqq[1] + s0 - 2.f * d01;
        dist[2][m] = sqq[2] + s0 - 2.f * d02;
        dist[3][m] = sqq[3] + s0 - 2.f * d03;
        dist[0][m2] = sqq[0] + s1v - 2.f * d10;
        dist[1][m2] = sqq[1] + s1v - 2.f * d11;
        dist[2][m2] = sqq[2] + s1v - 2.f * d12;
        dist[3][m2] = sqq[3] + s1v - 2.f * d13;
    }
    __syncthreads();
    // selection: wave w handles query w; lane owns 32 contiguous slots
    const int w = tid >> 6, lane = tid & 63;
    float* dw = dist[w];
    const int m0 = lane * 32;
    float bv = FLT_MAX; int bi = 1 << 30;
    for (int u = 0; u < 32; ++u) {
        float v = dw[m0 + u];
        if (v < bv) { bv = v; bi = m0 + u; }
    }
    int* op = idx_out + (size_t)(q0 + w) * KK;
    for (int t = 0; t < KK; ++t) {
        float v = bv; int i = bi;
        #pragma unroll
        for (int s = 1; s < 64; s <<= 1) {
            float v2 = __shfl_xor(v, s); int i2 = __shfl_xor(i, s);
            if (v2 < v || (v2 == v && i2 < i)) { v = v2; i = i2; }
        }
        if (lane == 0) op[t] = bofs + i;        // store GLOBAL point index
        if ((i >> 5) == lane) {                 // owner lane rescans its chunk
            dw[i] = FLT_MAX;
            bv = FLT_MAX; bi = 1 << 30;
            for (int u = 0; u < 32; ++u) {
                float vv = dw[m0 + u];
                if (vv < bv) { bv = vv; bi = m0 + u; }
            }
        }
    }
}

// ---------------- Wt[c][j] build: [Wd | Wtail] transposed, zero-padded ----------------
__global__ __launch_bounds__(256) void wt_build_kernel(const float* __restrict__ W,
                                                       float* __restrict__ Wt,
                                                       int D, int Dp, int C) {
    int i = blockIdx.x * 256 + threadIdx.x;
    if (i < 2 * C * Dp) {
        int c = i / Dp, j = i % Dp;
        float v = 0.f;
        if (j < D) {
            v = (c < C) ? (W[j * C + c] - W[(D + j) * C + c])
                        : W[(D + j) * C + (c - C)];
        }
        Wt[i] = v;
    }
}

// ---------------- X[TOT,Dp] @ Wt^T -> basexw[TOT,2C] ----------------
template <int NJ4, int C2>
__global__ __launch_bounds__(256) void xw_gemm_kernel(const float* __restrict__ x, int ldx,
                                                      const float* __restrict__ Wt,
                                                      float* __restrict__ bx) {
    constexpr int PG = 256 / C2;   // point groups
    constexpr int PTS = 16 / PG;   // points per thread
    __shared__ float4 Xs[16][NJ4];
    const int tid = threadIdx.x;
    const int p0 = blockIdx.x * 16;
    for (int i = tid; i < 16 * NJ4; i += 256) {
        int r = i / NJ4, j4 = i % NJ4;
        Xs[r][j4] = *reinterpret_cast<const float4*>(x + (size_t)(p0 + r) * ldx + j4 * 4);
    }
    __syncthreads();
    const int c = tid % C2, pg = tid / C2;
    const float4* wrow = reinterpret_cast<const float4*>(Wt + (size_t)c * (NJ4 * 4));
    float acc[PTS];
    #pragma unroll
    for (int u = 0; u < PTS; ++u) acc[u] = 0.f;
    #pragma unroll
    for (int j4 = 0; j4 < NJ4; ++j4) {
        float4 w4 = wrow[j4];
        #pragma unroll
        for (int u = 0; u < PTS; ++u) {
            float4 x4 = Xs[pg * PTS + u][j4];
            acc[u] += x4.x * w4.x + x4.y * w4.y + x4.z * w4.z + x4.w * w4.w;
        }
    }
    #pragma unroll
    for (int u = 0; u < PTS; ++u)
        bx[(size_t)(p0 + pg * PTS + u) * C2 + c] = acc[u];
}

// ---------------- edge pass: gather XW, stats + per-point max/min ----------------
template <int C>
__global__ __launch_bounds__(256) void edge_pass_kernel(const float* __restrict__ bx,
                                                        const int* __restrict__ idx,
                                                        float* __restrict__ psum,
                                                        float* __restrict__ psum2,
                                                        float* __restrict__ mmax,
                                                        float* __restrict__ mmin) {
    constexpr int PT = 256 / C;
    constexpr int C2 = 2 * C;
    __shared__ int sidx[PT][KK];
    __shared__ float red[256];
    const int tid = threadIdx.x;
    const int c = tid % C;
    const int pl = tid / C;
    float s1 = 0.f, s2 = 0.f;
    const int NT = TOT / PT;
    for (int t = blockIdx.x; t < NT; t += EBLK) {
        const int p0 = t * PT;
        __syncthreads();
        if (tid < PT * KK) sidx[tid / KK][tid % KK] = idx[(size_t)p0 * KK + tid];
        __syncthreads();
        const int p = p0 + pl;
        const float bv = bx[(size_t)p * C2 + c];
        float A = 0.f, Q = 0.f, M = -FLT_MAX, mn = FLT_MAX;
        #pragma unroll
        for (int k = 0; k < KK; ++k) {
            float v = bx[(size_t)sidx[pl][k] * C2 + C + c];
            A += v; Q += v * v; M = fmaxf(M, v); mn = fminf(mn, v);
        }
        s1 += (float)KK * bv + A;
        s2 += (float)KK * bv * bv + 2.f * bv * A + Q;
        mmax[(size_t)p * C + c] = bv + M;
        mmin[(size_t)p * C + c] = bv + mn;
    }
    red[tid] = s1;
    __syncthreads();
    if (tid < C) {
        float v = red[tid];
        #pragma unroll
        for (int u = 1; u < PT; ++u) v += red[tid + u * C];
        psum[(size_t)blockIdx.x * C + tid] = v;
    }
    __syncthreads();
    red[tid] = s2;
    __syncthreads();
    if (tid < C) {
        float v = red[tid];
        #pragma unroll
        for (int u = 1; u < PT; ++u) v += red[tid + u * C];
        psum2[(size_t)blockIdx.x * C + tid] = v;
    }
}

// ---------------- BN stats reduce -> alpha/beta ----------------
__global__ __launch_bounds__(256) void bn_reduce_kernel(
        const float* __restrict__ psum, const float* __restrict__ psum2,
        int npart, int C, const float* __restrict__ g, const float* __restrict__ bb,
        float inv_cnt, float* __restrict__ alpha, float* __restrict__ beta) {
    const int c = blockIdx.x;
    const int tid = threadIdx.x;
    __shared__ float r1[256], r2[256];
    float s1 = 0.f, s2 = 0.f;
    for (int i = tid; i < npart; i += 256) {
        s1 += psum[(size_t)i * C + c];
        s2 += psum2[(size_t)i * C + c];
    }
    r1[tid] = s1; r2[tid] = s2;
    __syncthreads();
    for (int s = 128; s > 0; s >>= 1) {
        if (tid < s) { r1[tid] += r1[tid + s]; r2[tid] += r2[tid + s]; }
        __syncthreads();
    }
    if (tid == 0) {
        float mean = r1[0] * inv_cnt;
        float var = r2[0] * inv_cnt - mean * mean;
        float a = g[c] * rsqrtf(var + 1e-5f);
        alpha[c] = a;
        beta[c] = bb[c] - mean * a;
    }
}

// ---------------- edge finalize: pick max/min by sign(alpha), affine+leaky ----------------
template <int C>
__global__ __launch_bounds__(256) void edge_finalize_kernel(const float* __restrict__ mmax,
                                                            const float* __restrict__ mmin,
                                                            const float* __restrict__ alpha,
                                                            const float* __restrict__ beta,
                                                            float* __restrict__ xc_slice) {
    constexpr int CQ = C / 4;
    int i4 = blockIdx.x * 256 + threadIdx.x;
    if (i4 < TOT * CQ) {
        int p = i4 / CQ, cq = i4 - p * CQ;
        float4 M4 = reinterpret_cast<const float4*>(mmax)[i4];
        float4 m4 = reinterpret_cast<const float4*>(mmin)[i4];
        float4 a4 = reinterpret_cast<const float4*>(alpha)[cq];
        float4 b4 = reinterpret_cast<const float4*>(beta)[cq];
        float4 o;
        o.x = leaky(a4.x * (a4.x >= 0.f ? M4.x : m4.x) + b4.x);
        o.y = leaky(a4.y * (a4.y >= 0.f ? M4.y : m4.y) + b4.y);
        o.z = leaky(a4.z * (a4.z >= 0.f ? M4.z : m4.z) + b4.z);
        o.w = leaky(a4.w * (a4.w >= 0.f ? M4.w : m4.w) + b4.w);
        *reinterpret_cast<float4*>(xc_slice + (size_t)p * 256 + cq * 4) = o;
    }
}

// ---------------- Wf transpose: [256][1024] -> [1024][256] ----------------
__global__ __launch_bounds__(256) void wft_build_kernel(const float* __restrict__ Wf,
                                                        float* __restrict__ Wft) {
    int i = blockIdx.x * 256 + threadIdx.x;
    if (i < 256 * 1024) {
        int e = i / 1024, o = i - e * 1024;
        Wft[(size_t)o * 256 + e] = Wf[i];
    }
}

// ---------------- conv_final fused: stats + per-batch max/min partials ----------------
__global__ __launch_bounds__(256) void fc_fused_kernel(const float* __restrict__ xc,
                                                       const float* __restrict__ Wft,
                                                       float* __restrict__ psum,
                                                       float* __restrict__ psum2,
                                                       float* __restrict__ pmax,
                                                       float* __restrict__ pmin) {
    __shared__ float4 rows[16][64];   // 16 points x 256 feats
    const int tid = threadIdx.x;
    const int b = blockIdx.x >> 5, jb = blockIdx.x & 31;
    float s1[4] = {0.f, 0.f, 0.f, 0.f}, s2[4] = {0.f, 0.f, 0.f, 0.f};
    float gx[4], gn[4];
    #pragma unroll
    for (int i = 0; i < 4; ++i) { gx[i] = -FLT_MAX; gn[i] = FLT_MAX; }
    for (int t = jb; t < 128; t += 32) {
        const int p0 = b * NP + t * 16;
        __syncthreads();
        for (int i = tid; i < 16 * 64; i += 256)
            rows[i >> 6][i & 63] = reinterpret_cast<const float4*>(xc)[(size_t)p0 * 64 + i];
        __syncthreads();
        float h[4][16];
        #pragma unroll
        for (int i = 0; i < 4; ++i)
            #pragma unroll
            for (int q = 0; q < 16; ++q) h[i][q] = 0.f;
        for (int e4 = 0; e4 < 64; ++e4) {
            float4 w4[4];
            #pragma unroll
            for (int i = 0; i < 4; ++i)
                w4[i] = reinterpret_cast<const float4*>(Wft)[(size_t)(tid + i * 256) * 64 + e4];
            #pragma unroll
            for (int q = 0; q < 16; ++q) {
                float4 r = rows[q][e4];
                #pragma unroll
                for (int i = 0; i < 4; ++i)
                    h[i][q] += r.x * w4[i].x + r.y * w4[i].y + r.z * w4[i].z + r.w * w4[i].w;
            }
        }
        #pragma unroll
        for (int i = 0; i < 4; ++i)
            #pragma unroll
            for (int q = 0; q < 16; ++q) {
                float v = h[i][q];
                s1[i] += v; s2[i] += v * v;
                gx[i] = fmaxf(gx[i], v); gn[i] = fminf(gn[i], v);
            }
    }
    #pragma unroll
    for (int i = 0; i < 4; ++i) {
        const size_t o = (size_t)blockIdx.x * 1024 + tid + i * 256;
        psum[o] = s1[i]; psum2[o] = s2[i];
        pmax[o] = gx[i]; pmin[o] = gn[i];
    }
}

// ---------------- gfeat finalize ----------------
__global__ __launch_bounds__(256) void gfeat_final_kernel(const float* __restrict__ pmax,
                                                          const float* __restrict__ pmin,
                                                          const float* __restrict__ alpha,
                                                          const float* __restrict__ beta,
                                                          float* __restrict__ gfeat) {
    int i = blockIdx.x * 256 + threadIdx.x;
    if (i < NB * 1024) {
        int b = i >> 10, c = i & 1023;
        float mx = -FLT_MAX, mn = FLT_MAX;
        for (int j = 0; j < 32; ++j) {
            size_t o = (size_t)((b << 5) + j) * 1024 + c;
            mx = fmaxf(mx, pmax[o]);
            mn = fminf(mn, pmin[o]);
        }
        float a = alpha[c];
        gfeat[i] = leaky(a * (a >= 0.f ? mx : mn) + beta[c]);
    }
}

// ---------------- tiny classifier ----------------
__global__ __launch_bounds__(256) void gemm_small(const float* __restrict__ A,
                                                  const float* __restrict__ W,
                                                  const float* __restrict__ bias,
                                                  float* __restrict__ out,
                                                  int M, int Kd, int Nd) {
    int i = blockIdx.x * 256 + threadIdx.x;
    if (i < M * Nd) {
        int m = i / Nd, c = i - m * Nd;
        float s = bias[c];
        const float* a = A + (size_t)m * Kd;
        for (int e = 0; e < Kd; ++e) s += a[e] * W[(size_t)e * Nd + c];
        out[i] = s;
    }
}

__global__ __launch_bounds__(256) void bn_rows_kernel(const float* __restrict__ z,
                                                      const float* __restrict__ g,
                                                      const float* __restrict__ bb,
                                                      float* __restrict__ out, int C) {
    int c = blockIdx.x * 256 + threadIdx.x;
    if (c < C) {
        float s = 0.f, s2 = 0.f;
        for (int b = 0; b < NB; ++b) {
            float v = z[(size_t)b * C + c];
            s += v; s2 += v * v;
        }
        float mean = s * (1.f / NB);
        float var = s2 * (1.f / NB) - mean * mean;
        float a = g[c] * rsqrtf(var + 1e-5f);
        float be = bb[c] - mean * a;
        for (int b = 0; b < NB; ++b) {
            float v = a * z[(size_t)b * C + c] + be;
            out[(size_t)b * C + c] = leaky(v);
        }
    }
}

} // namespace

extern "C" void kernel_launch(void* const* d_in, const int* in_sizes, int n_in,
                              void* d_out, int out_size, void* d_ws, size_t ws_size,
                              hipStream_t stream) {
    (void)in_sizes; (void)n_in; (void)out_size; (void)ws_size;
    const float* pos = (const float*)d_in[0];
    const float* W1  = (const float*)d_in[1];
    const float* g1  = (const float*)d_in[2];
    const float* b1  = (const float*)d_in[3];
    const float* W2  = (const float*)d_in[4];
    const float* g2  = (const float*)d_in[5];
    const float* b2  = (const float*)d_in[6];
    const float* W3  = (const float*)d_in[7];
    const float* g3  = (const float*)d_in[8];
    const float* b3  = (const float*)d_in[9];
    const float* Wf  = (const float*)d_in[10];
    const float* gf  = (const float*)d_in[11];
    const float* bf  = (const float*)d_in[12];
    const float* W4  = (const float*)d_in[13];
    const float* b4  = (const float*)d_in[14];
    const float* g4  = (const float*)d_in[15];
    const float* be4 = (const float*)d_in[16];
    const float* W5  = (const float*)d_in[17];
    const float* b5  = (const float*)d_in[18];
    const float* g5  = (const float*)d_in[19];
    const float* be5 = (const float*)d_in[20];
    const float* W6  = (const float*)d_in[21];
    const float* b6  = (const float*)d_in[22];
    float* out = (float*)d_out;

    float* ws = (float*)d_ws;
    size_t off = 0;
    int*   idx    = (int*)ws;      off += (size_t)TOT * KK;          // 2.6 MB
    float* pos4   = ws + off;      off += (size_t)TOT * 4;
    float* sq     = ws + off;      off += (size_t)TOT;
    float* Wt     = ws + off;      off += 256 * 64;
    float* Wft    = ws + off;      off += 1024 * 256;                // 1 MB
    float* basexw = ws + off;      off += (size_t)TOT * 256;         // 32 MB
    float* mmax   = ws + off;      off += (size_t)TOT * 128;         // 16 MB
    float* mmin   = ws + off;      off += (size_t)TOT * 128;         // 16 MB
    float* xc     = ws + off;      off += (size_t)TOT * 256;         // 32 MB
    float* psum   = ws + off;      off += (size_t)512 * 1024;        // 2 MB
    float* psum2  = ws + off;      off += (size_t)512 * 1024;
    float* pmax   = ws + off;      off += (size_t)512 * 1024;
    float* pmin   = ws + off;      off += (size_t)512 * 1024;
    float* alpha  = ws + off;      off += 1024;
    float* beta   = ws + off;      off += 1024;
    float* gfeat  = ws + off;      off += NB * 1024;
    float* z4     = ws + off;      off += NB * 512;
    float* h4     = ws + off;      off += NB * 512;
    float* z5     = ws + off;      off += NB * 256;
    float* h5     = ws + off;      off += NB * 256;
    // total ~116 MB

    const int npts_blk = (TOT + 255) / 256;

    // ---------- Layer 1 (D=3 padded to 4, C=64) ----------
    pos4_kernel<<<npts_blk, 256, 0, stream>>>(pos, pos4);
    sq4_kernel<<<npts_blk, 256, 0, stream>>>(pos4, 4, 1, sq);
    knn4_kernel<1><<<TOT / 4, 256, 0, stream>>>(pos4, 4, sq, idx);
    wt_build_kernel<<<2, 256, 0, stream>>>(W1, Wt, 3, 4, 64);
    xw_gemm_kernel<1, 128><<<TOT / 16, 256, 0, stream>>>(pos4, 4, Wt, basexw);
    edge_pass_kernel<64><<<EBLK, 256, 0, stream>>>(basexw, idx, psum, psum2, mmax, mmin);
    bn_reduce_kernel<<<64, 256, 0, stream>>>(psum, psum2, EBLK, 64, g1, b1,
                                             1.f / (float)(TOT * KK), alpha, beta);
    edge_finalize_kernel<64><<<TOT * 16 / 256, 256, 0, stream>>>(mmax, mmin, alpha, beta, xc + 0);

    // ---------- Layer 2 (D=64, C=64), input x1 = xc[:,0:64] ----------
    sq4_kernel<<<npts_blk, 256, 0, stream>>>(xc + 0, 256, 16, sq);
    knn4_kernel<16><<<TOT / 4, 256, 0, stream>>>(xc + 0, 256, sq, idx);
    wt_build_kernel<<<32, 256, 0, stream>>>(W2, Wt, 64, 64, 64);
    xw_gemm_kernel<16, 128><<<TOT / 16, 256, 0, stream>>>(xc + 0, 256, Wt, basexw);
    edge_pass_kernel<64><<<EBLK, 256, 0, stream>>>(basexw, idx, psum, psum2, mmax, mmin);
    bn_reduce_kernel<<<64, 256, 0, stream>>>(psum, psum2, EBLK, 64, g2, b2,
                                             1.f / (float)(TOT * KK), alpha, beta);
    edge_finalize_kernel<64><<<TOT * 16 / 256, 256, 0, stream>>>(mmax, mmin, alpha, beta, xc + 64);

    // ---------- Layer 3 (D=64, C=128), input x2 = xc[:,64:128] ----------
    sq4_kernel<<<npts_blk, 256, 0, stream>>>(xc + 64, 256, 16, sq);
    knn4_kernel<16><<<TOT / 4, 256, 0, stream>>>(xc + 64, 256, sq, idx);
    wt_build_kernel<<<64, 256, 0, stream>>>(W3, Wt, 64, 64, 128);
    xw_gemm_kernel<16, 256><<<TOT / 16, 256, 0, stream>>>(xc + 64, 256, Wt, basexw);
    edge_pass_kernel<128><<<EBLK, 256, 0, stream>>>(basexw, idx, psum, psum2, mmax, mmin);
    bn_reduce_kernel<<<128, 256, 0, stream>>>(psum, psum2, EBLK, 128, g3, b3,
                                              1.f / (float)(TOT * KK), alpha, beta);
    edge_finalize_kernel<128><<<TOT * 32 / 256, 256, 0, stream>>>(mmax, mmin, alpha, beta, xc + 128);

    // ---------- conv_final + global max pool ----------
    wft_build_kernel<<<1024, 256, 0, stream>>>(Wf, Wft);
    fc_fused_kernel<<<512, 256, 0, stream>>>(xc, Wft, psum, psum2, pmax, pmin);
    bn_reduce_kernel<<<1024, 256, 0, stream>>>(psum, psum2, 512, 1024, gf, bf,
                                               1.f / (float)TOT, alpha, beta);
    gfeat_final_kernel<<<64, 256, 0, stream>>>(pmax, pmin, alpha, beta, gfeat);

    // ---------- classifier ----------
    gemm_small<<<(NB * 512 + 255) / 256, 256, 0, stream>>>(gfeat, W4, b4, z4, NB, 1024, 512);
    bn_rows_kernel<<<2, 256, 0, stream>>>(z4, g4, be4, h4, 512);
    gemm_small<<<(NB * 256 + 255) / 256, 256, 0, stream>>>(h4, W5, b5, z5, NB, 512, 256);
    bn_rows_kernel<<<1, 256, 0, stream>>>(z5, g5, be5, h5, 256);
    gemm_small<<<(NB * 40 + 255) / 256, 256, 0, stream>>>(h5, W6, b6, out, NB, 256, 40);
}